// Round 3
// baseline (10285.563 us; speedup 1.0000x reference)
//
#include <hip/hip_runtime.h>

typedef __attribute__((ext_vector_type(4))) float f32x4;
typedef __attribute__((ext_vector_type(8))) short s16x8;

#define MFMA16(a, b, c) __builtin_amdgcn_mfma_f32_16x16x32_bf16((a), (b), (c), 0, 0, 0)

// ---------- bf16 helpers (RNE) ----------
__device__ inline unsigned short f2bf(float f) {
    unsigned int u = __float_as_uint(f);
    return (unsigned short)((u + 0x7FFFu + ((u >> 16) & 1u)) >> 16);
}
__device__ inline float bf2f(unsigned short b) {
    return __uint_as_float(((unsigned int)b) << 16);
}

// ---------- pack W [K][1024] f32 -> THREE bf16 levels, MFMA-B layout ----------
// W = L1 + L2 + L3 + r, |r| <= |W|*2^-27 (each subtraction is exact: Sterbenz).
// layout: o = kt*32768 + n*32 + ki (kt=k/32, ki=k%32); lane's B-frag is 16
// contiguous bytes at ((kt*1024+n)*32 + (lane>>4)*8)*2.
__global__ __launch_bounds__(256) void k_pack3(const float* __restrict__ W,
                                               unsigned short* __restrict__ L1,
                                               unsigned short* __restrict__ L2,
                                               unsigned short* __restrict__ L3,
                                               int K) {
    int idx = blockIdx.x * 256 + threadIdx.x;   // idx = k*1024 + n (coalesced)
    if (idx >= K * 1024) return;
    int k = idx >> 10;
    int n = idx & 1023;
    float x = W[idx];
    unsigned short h1 = f2bf(x);  float r1 = x - bf2f(h1);
    unsigned short h2 = f2bf(r1); float r2 = r1 - bf2f(h2);
    unsigned short h3 = f2bf(r2);
    size_t o = ((size_t)(k >> 5) << 15) + ((size_t)n << 5) + (k & 31);
    L1[o] = h1; L2[o] = h2; L3[o] = h3;
}

// ---------- fused main kernel: 128 blocks x 16 batch rows, 32 steps ----------
// 16 waves; wave w owns cols [w*64, w*64+64). Thread (w,lane) owns state for
// rows lhi*4+fr x cols w*64+nt*16+llo (the 16x16x32 MFMA C/D layout).
#define FSTR 776  // fused-tile LDS row stride in floats (768+8: de-conflicts banks)
__global__ __launch_bounds__(1024) void k_main(const float* __restrict__ fused,
                                               const unsigned short* __restrict__ Wi1,
                                               const unsigned short* __restrict__ Wi2,
                                               const unsigned short* __restrict__ Wi3,
                                               const float* __restrict__ b_in,
                                               const unsigned short* __restrict__ Wr1,
                                               const unsigned short* __restrict__ Wr2,
                                               const unsigned short* __restrict__ Wr3,
                                               const float* __restrict__ b_rec,
                                               const float* __restrict__ rdec,
                                               const float* __restrict__ rfrq,
                                               const float* __restrict__ W_out,
                                               const float* __restrict__ b_out,
                                               float* __restrict__ out) {
    __shared__ __align__(16) char smem[65536];
    const int tid = threadIdx.x;
    const int w = tid >> 6, lane = tid & 63;
    const int llo = lane & 15, lhi = lane >> 4;
    const int r0 = blockIdx.x * 16;

    float dec[4], frq[4], brc[4], bin[4];
    int cols[4];
#pragma unroll
    for (int nt = 0; nt < 4; ++nt) {
        int c = w * 64 + nt * 16 + llo;
        cols[nt] = c;
        // f64 sigmoid -> correctly-rounded f32 (matches np f32 sigmoid to <=1 ulp)
        dec[nt] = (float)(0.55 + 0.4 / (1.0 + exp(-(double)rdec[c])));
        frq[nt] = (float)(0.10 + 0.9 / (1.0 + exp(-(double)rfrq[c])));
        brc[nt] = b_rec[c];
        bin[nt] = b_in[c];
    }

    // ---- phase A: stage fused[r0:r0+16][0:768] into LDS (stride FSTR) ----
    float* fl = (float*)smem;
    for (int i = tid; i < 16 * 768; i += 1024) {
        int rr = i / 768, cc = i - rr * 768;
        fl[rr * FSTR + cc] = fused[(size_t)(r0 + rr) * 768 + cc];
    }
    __syncthreads();

    // ---- phase B: base = fused @ W_in + b_in, 3x3-level split, 6 passes ----
    // kept pairs (1,1),(1,2),(2,1),(2,2),(1,3),(3,1): residual ~|ab|*2^-27.
    f32x4 bacc[4] = {};
    for (int kt = 0; kt < 24; ++kt) {
        const float* ap = fl + llo * FSTR + kt * 32 + lhi * 8;
        s16x8 a1, a2, a3;
#pragma unroll
        for (int j = 0; j < 8; ++j) {
            float x = ap[j];
            unsigned short h1 = f2bf(x);  float r1 = x - bf2f(h1);
            unsigned short h2 = f2bf(r1); float r2 = r1 - bf2f(h2);
            a1[j] = (short)h1; a2[j] = (short)h2; a3[j] = (short)f2bf(r2);
        }
#pragma unroll
        for (int nt = 0; nt < 4; ++nt) {
            size_t boff = ((size_t)(kt * 1024 + cols[nt]) << 5) + lhi * 8;
            s16x8 b1 = *(const s16x8*)&Wi1[boff];
            s16x8 b2 = *(const s16x8*)&Wi2[boff];
            s16x8 b3 = *(const s16x8*)&Wi3[boff];
            bacc[nt] = MFMA16(a1, b1, bacc[nt]);
            bacc[nt] = MFMA16(a1, b2, bacc[nt]);
            bacc[nt] = MFMA16(a2, b1, bacc[nt]);
            bacc[nt] = MFMA16(a2, b2, bacc[nt]);
            bacc[nt] = MFMA16(a1, b3, bacc[nt]);
            bacc[nt] = MFMA16(a3, b1, bacc[nt]);
        }
    }
    float base_[4][4];
#pragma unroll
    for (int nt = 0; nt < 4; ++nt)
#pragma unroll
        for (int fr = 0; fr < 4; ++fr)
            base_[nt][fr] = __fadd_rn(bacc[nt][fr], bin[nt]);
    __syncthreads();  // fused tile dead; smem becomes spike double-buffer

    // ---- phase C: 32-step recurrence; spikes are EXACT in bf16 ----
    float mem[4][4] = {}, res[4][4] = {}, pooled[4][4] = {};
    for (int t = 0; t < 32; ++t) {
        f32x4 acc[4] = {};
        if (t > 0) {
            const char* abase = smem + ((t - 1) & 1) * 32768 + llo * 2048;
            const int axor = (llo & 7) << 4;
#pragma unroll
            for (int kt = 0; kt < 32; ++kt) {
                s16x8 a = *(const s16x8*)(abase + ((kt * 64 + lhi * 16) ^ axor));
#pragma unroll
                for (int nt = 0; nt < 4; ++nt) {
                    size_t boff = ((size_t)(kt * 1024 + cols[nt]) << 5) + lhi * 8;
                    s16x8 b1 = *(const s16x8*)&Wr1[boff];
                    s16x8 b2 = *(const s16x8*)&Wr2[boff];
                    s16x8 b3 = *(const s16x8*)&Wr3[boff];
                    acc[nt] = MFMA16(a, b1, acc[nt]);
                    acc[nt] = MFMA16(a, b2, acc[nt]);
                    acc[nt] = MFMA16(a, b3, acc[nt]);
                }
            }
        }
        char* wbase = smem + (t & 1) * 32768;
#pragma unroll
        for (int nt = 0; nt < 4; ++nt) {
#pragma unroll
            for (int fr = 0; fr < 4; ++fr) {
                int row = lhi * 4 + fr;
                // exact np op order, no FMA contraction:
                float rec = (t > 0) ? __fadd_rn(acc[nt][fr], brc[nt]) : 0.f;
                float drive = __fadd_rn(base_[nt][fr], rec);
                float rnew = __fadd_rn(__fmul_rn(dec[nt], res[nt][fr]),
                                       __fmul_rn(frq[nt], mem[nt][fr]));
                float t1 = __fadd_rn(__fmul_rn(dec[nt], mem[nt][fr]), drive);
                float m_ = __fadd_rn(t1, -rnew);
                float sp = (m_ > 1.0f) ? 1.f : 0.f;
                res[nt][fr] = rnew;
                mem[nt][fr] = __fadd_rn(m_, -sp);
                pooled[nt][fr] += sp;
                int boff2 = row * 2048 + ((cols[nt] * 2) ^ ((row & 7) << 4));
                *(unsigned short*)(wbase + boff2) = (sp > 0.f) ? (unsigned short)0x3F80 : (unsigned short)0;
            }
        }
        __syncthreads();
    }

    // ---- phase D: pooled/32 (exact) -> LDS, then f64 dot with W_out ----
    float* plds = (float*)smem;
#pragma unroll
    for (int nt = 0; nt < 4; ++nt)
#pragma unroll
        for (int fr = 0; fr < 4; ++fr)
            plds[(lhi * 4 + fr) * 1024 + cols[nt]] = pooled[nt][fr] * 0.03125f;
    __syncthreads();
    if (tid < 256) {
        int row = tid >> 4, o = tid & 15;
        double s = 0.0;
        for (int h = 0; h < 1024; ++h)
            s += (double)plds[row * 1024 + h] * (double)W_out[h * 16 + o];
        out[(size_t)(r0 + row) * 16 + o] = __fadd_rn((float)s, b_out[o]);
    }
}

extern "C" void kernel_launch(void* const* d_in, const int* in_sizes, int n_in,
                              void* d_out, int out_size, void* d_ws, size_t ws_size,
                              hipStream_t stream) {
    const float* fused = (const float*)d_in[0];
    const float* W_in  = (const float*)d_in[1];
    const float* b_in  = (const float*)d_in[2];
    const float* W_rec = (const float*)d_in[3];
    const float* b_rec = (const float*)d_in[4];
    const float* W_out = (const float*)d_in[5];
    const float* b_out = (const float*)d_in[6];
    const float* rdec  = (const float*)d_in[7];
    const float* rfrq  = (const float*)d_in[8];

    // ws: Wrec L1/L2/L3 (3x2MB) + Win L1/L2/L3 (3x1.5MB) = 10.5 MB
    char* ws = (char*)d_ws;
    unsigned short* Wr1 = (unsigned short*)(ws);
    unsigned short* Wr2 = (unsigned short*)(ws + (2u << 20));
    unsigned short* Wr3 = (unsigned short*)(ws + (4u << 20));
    unsigned short* Wi1 = (unsigned short*)(ws + (6u << 20));
    unsigned short* Wi2 = (unsigned short*)(ws + (6u << 20) + (3u << 19));
    unsigned short* Wi3 = (unsigned short*)(ws + (6u << 20) + (6u << 19));
    float* out = (float*)d_out;

    hipLaunchKernelGGL(k_pack3, dim3(4096), dim3(256), 0, stream, W_rec, Wr1, Wr2, Wr3, 1024);
    hipLaunchKernelGGL(k_pack3, dim3(3072), dim3(256), 0, stream, W_in, Wi1, Wi2, Wi3, 768);
    hipLaunchKernelGGL(k_main, dim3(128), dim3(1024), 0, stream,
                       fused, Wi1, Wi2, Wi3, b_in, Wr1, Wr2, Wr3, b_rec,
                       rdec, rfrq, W_out, b_out, out);
}

// Round 4
// 1585.758 us; speedup vs baseline: 6.4862x; 6.4862x over previous
//
#include <hip/hip_runtime.h>

typedef __attribute__((ext_vector_type(4))) float f32x4;
typedef __attribute__((ext_vector_type(4))) int   i32x4;
typedef __attribute__((ext_vector_type(8))) short s16x8;

#define MFMA16(a, b, c)  __builtin_amdgcn_mfma_f32_16x16x32_bf16((a), (b), (c), 0, 0, 0)
#define MFMAI8(a, b, c)  __builtin_amdgcn_mfma_i32_16x16x64_i8((a), (b), (c), 0, 0, 0)

#define QINV (1.0f / 252.0f)

// ---------- bf16 helpers (RNE) ----------
__device__ inline unsigned short f2bf(float f) {
    unsigned int u = __float_as_uint(f);
    return (unsigned short)((u + 0x7FFFu + ((u >> 16) & 1u)) >> 16);
}
__device__ inline float bf2f(unsigned short b) {
    return __uint_as_float(((unsigned int)b) << 16);
}

// ---------- pack W [K][1024] f32 -> THREE bf16 levels (for W_in path) ----------
__global__ __launch_bounds__(256) void k_pack3(const float* __restrict__ W,
                                               unsigned short* __restrict__ L1,
                                               unsigned short* __restrict__ L2,
                                               unsigned short* __restrict__ L3,
                                               int K) {
    int idx = blockIdx.x * 256 + threadIdx.x;
    if (idx >= K * 1024) return;
    int k = idx >> 10;
    int n = idx & 1023;
    float x = W[idx];
    unsigned short h1 = f2bf(x);  float r1 = x - bf2f(h1);
    unsigned short h2 = f2bf(r1); float r2 = r1 - bf2f(h2);
    unsigned short h3 = f2bf(r2);
    size_t o = ((size_t)(k >> 5) << 15) + ((size_t)n << 5) + (k & 31);
    L1[o] = h1; L2[o] = h2; L3[o] = h3;
}

// ---------- per-column max|W_rec| -> t1[n] = max/126 ----------
__global__ __launch_bounds__(256) void k_colmax(const float* __restrict__ W,
                                                float* __restrict__ t1) {
    __shared__ float red[256];
    int n = blockIdx.x;
    float m = 0.f;
    for (int k = threadIdx.x; k < 1024; k += 256)
        m = fmaxf(m, fabsf(W[(size_t)k * 1024 + n]));
    red[threadIdx.x] = m;
    __syncthreads();
    for (int s = 128; s > 0; s >>= 1) {
        if (threadIdx.x < s) red[threadIdx.x] = fmaxf(red[threadIdx.x], red[threadIdx.x + s]);
        __syncthreads();
    }
    if (threadIdx.x == 0) t1[n] = fmaxf(red[0], 1e-30f) * (1.0f / 126.0f);
}

// ---------- pack W_rec -> 3 i8 digits, interleaved [kt][n][lvl][64] ----------
// byte offset = ((k>>6)*1024 + n)*192 + lvl*64 + (k&63)
__global__ __launch_bounds__(256) void k_packq(const float* __restrict__ W,
                                               const float* __restrict__ t1a,
                                               signed char* __restrict__ Q) {
    int idx = blockIdx.x * 256 + threadIdx.x;   // k*1024 + n
    int k = idx >> 10;
    int n = idx & 1023;
    float x = W[idx];
    float T1 = t1a[n];
    float T2 = T1 * QINV;
    float T3 = T2 * QINV;
    float q1 = rintf(x / T1);  float r1 = fmaf(-q1, T1, x);
    float q2 = rintf(r1 / T2); float r2 = fmaf(-q2, T2, r1);
    float q3 = rintf(r2 / T3);
    size_t o = ((size_t)((k >> 6) * 1024 + n)) * 192 + (k & 63);
    Q[o]       = (signed char)(int)q1;
    Q[o + 64]  = (signed char)(int)q2;
    Q[o + 128] = (signed char)(int)q3;
}

// ---------- fused main kernel: 128 blocks x 16 batch rows, 32 steps ----------
#define FSTR 770  // fused-tile LDS row stride (768+2): lane bank = 2*llo+8*lhi+j, 2-way max
__global__ __launch_bounds__(1024, 1) void k_main(const float* __restrict__ fused,
                                                  const unsigned short* __restrict__ Wi1,
                                                  const unsigned short* __restrict__ Wi2,
                                                  const unsigned short* __restrict__ Wi3,
                                                  const float* __restrict__ b_in,
                                                  const signed char* __restrict__ WrQ,
                                                  const float* __restrict__ t1a,
                                                  const float* __restrict__ b_rec,
                                                  const float* __restrict__ rdec,
                                                  const float* __restrict__ rfrq,
                                                  const float* __restrict__ W_out,
                                                  const float* __restrict__ b_out,
                                                  float* __restrict__ out) {
    // LDS map: phases A/B: fused tile f32 [16][FSTR] @0 (49280 B)
    //          always:     param table dec/frq/t1 @ 52K (3 x 4KB)
    //          phase C:    spike dbuf i8 2 x [16][1024] (XOR-swizzled) @0 (32KB)
    //          phase D:    pooled f32 [16][1024] @0 (64KB)
    __shared__ __align__(16) char smem[65536];
    const int tid = threadIdx.x;
    const int w = tid >> 6, lane = tid & 63;
    const int llo = lane & 15, lhi = lane >> 4;
    const int r0 = blockIdx.x * 16;

    float* ldsDec = (float*)(smem + 53248);
    float* ldsFrq = (float*)(smem + 53248 + 4096);
    float* ldsT1  = (float*)(smem + 53248 + 8192);

    // param table (each thread covers its own 4 cols; redundant same-value writes OK)
    float brc[4];
#pragma unroll
    for (int nt = 0; nt < 4; ++nt) {
        int c = w * 64 + nt * 16 + llo;
        ldsDec[c] = (float)(0.55 + 0.4 / (1.0 + exp(-(double)rdec[c])));
        ldsFrq[c] = (float)(0.10 + 0.9 / (1.0 + exp(-(double)rfrq[c])));
        ldsT1[c]  = t1a[c];
        brc[nt] = b_rec[c];
    }

    // ---- phase A: stage fused[r0:r0+16][0:768] into LDS ----
    float* fl = (float*)smem;
    for (int i = tid; i < 16 * 768; i += 1024) {
        int rr = i / 768, cc = i - rr * 768;
        fl[rr * FSTR + cc] = fused[(size_t)(r0 + rr) * 768 + cc];
    }
    __syncthreads();

    // ---- phase B: base = fused @ W_in + b_in (3x3-level bf16, 6 passes) ----
    f32x4 bacc[4] = {};
    for (int kt = 0; kt < 24; ++kt) {
        const float* ap = fl + llo * FSTR + kt * 32 + lhi * 8;
        s16x8 a1v, a2v, a3v;
#pragma unroll
        for (int j = 0; j < 8; ++j) {
            float x = ap[j];
            unsigned short h1 = f2bf(x);  float r1 = x - bf2f(h1);
            unsigned short h2 = f2bf(r1); float r2 = r1 - bf2f(h2);
            a1v[j] = (short)h1; a2v[j] = (short)h2; a3v[j] = (short)f2bf(r2);
        }
#pragma unroll
        for (int nt = 0; nt < 4; ++nt) {
            int c = w * 64 + nt * 16 + llo;
            size_t boff = ((size_t)(kt * 1024 + c) << 5) + lhi * 8;
            s16x8 b1 = *(const s16x8*)&Wi1[boff];
            s16x8 b2 = *(const s16x8*)&Wi2[boff];
            s16x8 b3 = *(const s16x8*)&Wi3[boff];
            bacc[nt] = MFMA16(a1v, b1, bacc[nt]);
            bacc[nt] = MFMA16(a1v, b2, bacc[nt]);
            bacc[nt] = MFMA16(a2v, b1, bacc[nt]);
            bacc[nt] = MFMA16(a2v, b2, bacc[nt]);
            bacc[nt] = MFMA16(a1v, b3, bacc[nt]);
            bacc[nt] = MFMA16(a3v, b1, bacc[nt]);
        }
    }
    // base_ (t=0 drive) and base2 = base_ + brc (t>0 drive prefix)
    float base2[4][4];
    float mem[4][4], res[4][4];
    unsigned int pooled_pk[4] = {0, 0, 0, 0};
#pragma unroll
    for (int nt = 0; nt < 4; ++nt) {
        int c = w * 64 + nt * 16 + llo;
        float bb = b_in[c];
#pragma unroll
        for (int fr = 0; fr < 4; ++fr) {
            float b0 = __fadd_rn(bacc[nt][fr], bb);
            base2[nt][fr] = __fadd_rn(b0, brc[nt]);
            // ---- step t = 0 inline (rec = 0, drive = base_) ----
            float rnew = 0.f;                       // dec*0 + frq*0
            float m_ = __fadd_rn(0.f, b0);          // dec*0 + drive - 0
            int s = (m_ > 1.0f) ? 1 : 0;
            res[nt][fr] = rnew;
            mem[nt][fr] = __fadd_rn(m_, -(float)s);
            pooled_pk[nt] += (unsigned int)s << (8 * fr);
        }
    }
    __syncthreads();  // fused tile dead; smem[0:32K) becomes spike dbuf

    // write t=0 spikes into buf0
    {
        char* wb = smem;
#pragma unroll
        for (int nt = 0; nt < 4; ++nt) {
            int c = w * 64 + nt * 16 + llo;
#pragma unroll
            for (int fr = 0; fr < 4; ++fr) {
                int row = lhi * 4 + fr;
                int boff = (row * 1024 + c) ^ ((row & 7) << 4);
                *(unsigned char*)(wb + boff) = (unsigned char)((pooled_pk[nt] >> (8 * fr)) & 1u);
            }
        }
    }
    __syncthreads();

    // ---- phase C: steps 1..31 ----
    const int ax = (llo & 7) << 4;
    for (int t = 1; t < 32; ++t) {
        i32x4 q1a[4] = {}, q2a[4] = {}, q3a[4] = {};
        {
            const char* ab = smem + ((t - 1) & 1) * 16384 + llo * 1024;
            const signed char* bp0 = WrQ + ((size_t)(w * 64 + llo)) * 192 + lhi * 16;
#pragma unroll 2
            for (int kt = 0; kt < 16; ++kt) {
                i32x4 A = *(const i32x4*)(ab + ((kt * 64 + lhi * 16) ^ ax));
                const signed char* bp = bp0 + (size_t)kt * 196608;
#pragma unroll
                for (int nt = 0; nt < 4; ++nt) {
                    const signed char* b = bp + nt * 3072;   // (16 cols)*192
                    i32x4 B1 = *(const i32x4*)(b);
                    i32x4 B2 = *(const i32x4*)(b + 64);
                    i32x4 B3 = *(const i32x4*)(b + 128);
                    q1a[nt] = MFMAI8(A, B1, q1a[nt]);
                    q2a[nt] = MFMAI8(A, B2, q2a[nt]);
                    q3a[nt] = MFMAI8(A, B3, q3a[nt]);
                }
            }
        }
        char* wb = smem + (t & 1) * 16384;
#pragma unroll
        for (int nt = 0; nt < 4; ++nt) {
            int c = w * 64 + nt * 16 + llo;
            float dcc = ldsDec[c], fqc = ldsFrq[c], t1c = ldsT1[c];
#pragma unroll
            for (int fr = 0; fr < 4; ++fr) {
                int row = lhi * 4 + fr;
                // rec = t1 * (S1 + (S2 + S3*q)*q)   (exact i32 sums, Horner combine)
                float s3 = (float)q3a[nt][fr];
                float s2 = fmaf(s3, QINV, (float)q2a[nt][fr]);
                float rec = __fmul_rn(fmaf(s2, QINV, (float)q1a[nt][fr]), t1c);
                float drive = __fadd_rn(base2[nt][fr], rec);   // base + b_rec + rec
                float rnew = __fadd_rn(__fmul_rn(dcc, res[nt][fr]),
                                       __fmul_rn(fqc, mem[nt][fr]));
                float t1_ = __fadd_rn(__fmul_rn(dcc, mem[nt][fr]), drive);
                float m_ = __fadd_rn(t1_, -rnew);
                int s = (m_ > 1.0f) ? 1 : 0;
                res[nt][fr] = rnew;
                mem[nt][fr] = __fadd_rn(m_, -(float)s);
                pooled_pk[nt] += (unsigned int)s << (8 * fr);
                int boff = (row * 1024 + c) ^ ((row & 7) << 4);
                *(unsigned char*)(wb + boff) = (unsigned char)s;
            }
        }
        __syncthreads();
    }

    // ---- phase D: pooled/32 -> LDS, f64 dot with W_out ----
    float* plds = (float*)smem;
#pragma unroll
    for (int nt = 0; nt < 4; ++nt) {
        int c = w * 64 + nt * 16 + llo;
#pragma unroll
        for (int fr = 0; fr < 4; ++fr)
            plds[(lhi * 4 + fr) * 1024 + c] =
                (float)((pooled_pk[nt] >> (8 * fr)) & 255u) * 0.03125f;
    }
    __syncthreads();
    if (tid < 256) {
        int row = tid >> 4, o = tid & 15;
        double s = 0.0;
        for (int h = 0; h < 1024; ++h)
            s += (double)plds[row * 1024 + h] * (double)W_out[h * 16 + o];
        out[(size_t)(r0 + row) * 16 + o] = __fadd_rn((float)s, b_out[o]);
    }
}

extern "C" void kernel_launch(void* const* d_in, const int* in_sizes, int n_in,
                              void* d_out, int out_size, void* d_ws, size_t ws_size,
                              hipStream_t stream) {
    const float* fused = (const float*)d_in[0];
    const float* W_in  = (const float*)d_in[1];
    const float* b_in  = (const float*)d_in[2];
    const float* W_rec = (const float*)d_in[3];
    const float* b_rec = (const float*)d_in[4];
    const float* W_out = (const float*)d_in[5];
    const float* b_out = (const float*)d_in[6];
    const float* rdec  = (const float*)d_in[7];
    const float* rfrq  = (const float*)d_in[8];

    // ws: WrQ 3MB @0 | t1 4KB @3MB | Wi1/2/3 1.5MB each @3.25MB  (total ~7.75MB)
    char* ws = (char*)d_ws;
    signed char*    WrQ = (signed char*)(ws);
    float*          t1a = (float*)(ws + (3u << 20));
    unsigned short* Wi1 = (unsigned short*)(ws + (3u << 20) + (1u << 18));
    unsigned short* Wi2 = (unsigned short*)(ws + (3u << 20) + (1u << 18) + (3u << 19));
    unsigned short* Wi3 = (unsigned short*)(ws + (3u << 20) + (1u << 18) + (6u << 19));
    float* out = (float*)d_out;

    hipLaunchKernelGGL(k_colmax, dim3(1024), dim3(256), 0, stream, W_rec, t1a);
    hipLaunchKernelGGL(k_packq, dim3(4096), dim3(256), 0, stream, W_rec, t1a, WrQ);
    hipLaunchKernelGGL(k_pack3, dim3(3072), dim3(256), 0, stream, W_in, Wi1, Wi2, Wi3, 768);
    hipLaunchKernelGGL(k_main, dim3(128), dim3(1024), 0, stream,
                       fused, Wi1, Wi2, Wi3, b_in, WrQ, t1a, b_rec,
                       rdec, rfrq, W_out, b_out, out);
}